// Round 8
// baseline (59.651 us; speedup 1.0000x reference)
//
#include <hip/hip_runtime.h>
#include <math.h>

// Problem constants
#define E      4096
#define BATCH  8
#define COLB   256            // columns per block (64 lanes x float4)
#define KB     128            // k-rows per block (4 waves x 32)
#define NCOLB  (E / COLB)     // 16
#define NKB    (E / KB)       // 32

typedef float f32x4 __attribute__((ext_vector_type(4)));

// ---------------------------------------------------------------------------
// Kernel A: split-K partial GEMM for  yin @ (w + alpha*hebb)
//   partial[kBlock][b][col] = sum_{k in kBlock} yin[b][k] * (w[k][col] + alpha[k][col]*hebb[k][col])
// Deterministic: fixed partitioning, fixed reduction order, no atomics.
// All loads normal (R4/R5: nt loads force L3 misses, +17 us regression).
// Measured at ~5.6 TB/s delivered — at its delivery ceiling (R1/R2/R7 A/B).
// ---------------------------------------------------------------------------
__global__ __launch_bounds__(256) void partial_gemm_kernel(
    const float* __restrict__ yin,
    const float* __restrict__ hebb,
    const float* __restrict__ w,
    const float* __restrict__ alpha,
    float* __restrict__ partial)          // [NKB][BATCH][E]
{
    __shared__ __align__(16) float s_yin[BATCH * KB];        // 4 KiB
    __shared__ __align__(16) float s_red[4 * BATCH * COLB];  // 32 KiB

    const int t    = threadIdx.x;
    const int lane = t & 63;
    const int wave = t >> 6;              // 0..3
    const int colBlock = blockIdx.x;      // 0..15
    const int kBlock   = blockIdx.y;      // 0..31

    // Stage yin[b][kBlock*KB .. +KB) into LDS: 8 x 128 floats, float4 per thread
    {
        const int b   = t >> 5;           // 0..7
        const int off = (t & 31) * 4;     // 0..124
        const float4 v = *reinterpret_cast<const float4*>(
            yin + (size_t)b * E + (size_t)kBlock * KB + off);
        *reinterpret_cast<float4*>(&s_yin[b * KB + off]) = v;
    }
    __syncthreads();

    const int col0 = colBlock * COLB + lane * 4;

    float4 acc[BATCH];
#pragma unroll
    for (int b = 0; b < BATCH; ++b) acc[b] = make_float4(0.f, 0.f, 0.f, 0.f);

    const int kLocal0 = wave * (KB / 4);  // 32 k's per wave

#pragma unroll 2
    for (int kk = 0; kk < KB / 4; ++kk) {
        const int kL = kLocal0 + kk;
        const size_t row = (size_t)(kBlock * KB + kL) * E + col0;

        const float4 w4 = *reinterpret_cast<const float4*>(w + row);
        const float4 a4 = *reinterpret_cast<const float4*>(alpha + row);
        const float4 h4 = *reinterpret_cast<const float4*>(hebb + row);

        float4 m;
        m.x = w4.x + a4.x * h4.x;
        m.y = w4.y + a4.y * h4.y;
        m.z = w4.z + a4.z * h4.z;
        m.w = w4.w + a4.w * h4.w;

#pragma unroll
        for (int b = 0; b < BATCH; ++b) {
            const float yv = s_yin[b * KB + kL];
            acc[b].x = fmaf(yv, m.x, acc[b].x);
            acc[b].y = fmaf(yv, m.y, acc[b].y);
            acc[b].z = fmaf(yv, m.z, acc[b].z);
            acc[b].w = fmaf(yv, m.w, acc[b].w);
        }
    }

    // Store per-wave accumulators: layout s_red[wave][b][COLB]
#pragma unroll
    for (int b = 0; b < BATCH; ++b) {
        *reinterpret_cast<float4*>(&s_red[(wave * BATCH + b) * COLB + lane * 4]) = acc[b];
    }
    __syncthreads();

    // Reduce 4 waves -> partial.  col = t (coalesced LDS + global).
#pragma unroll
    for (int b = 0; b < BATCH; ++b) {
        const int col = t;
        const float s = s_red[(0 * BATCH + b) * COLB + col]
                      + s_red[(1 * BATCH + b) * COLB + col]
                      + s_red[(2 * BATCH + b) * COLB + col]
                      + s_red[(3 * BATCH + b) * COLB + col];
        partial[((size_t)kBlock * BATCH + b) * E + colBlock * COLB + col] = s;
    }
}

// ---------------------------------------------------------------------------
// Kernel BC (merged finalize + hebb update):
// Grid (32 col-stripes x 64 row-chunks), 256 threads.
//  1) every block recomputes yout[0][stripe] from the b=0 partial slice
//     (512 KB total, L2/L3-hot, kb-ascending order = bitwise same as yout).
//  2) rc==0 blocks also write the full yout for all 8 batches.
//  3) hebb tile update: rows rc*64..+64, cols stripe*128..+128,
//     hebb_out = (1-eta)*hebb + eta*yin[0][i]*yout0[j].  nt store (R7: >=).
// Deterministic; disjoint writes; no atomics.
// ---------------------------------------------------------------------------
#define STRIPE 128            // cols per stripe
#define RCHUNK 64             // rows per chunk

__global__ __launch_bounds__(256) void fused_bc_kernel(
    const float* __restrict__ input,
    const float* __restrict__ partial,    // [NKB][BATCH][E]
    const float* __restrict__ yin,
    const float* __restrict__ hebb,
    const float* __restrict__ eta_p,
    float* __restrict__ yout,
    float* __restrict__ hebb_out)
{
    const int cs = blockIdx.x;            // 0..31 col stripe
    const int rc = blockIdx.y;            // 0..63 row chunk
    const int t  = threadIdx.x;
    const int col0 = cs * STRIPE;

    __shared__ __align__(16) float s_y0[STRIPE];

    // 1) yout[0][stripe] (threads 0..127)
    if (t < STRIPE) {
        const int j = col0 + t;
        float s = input[j];               // input[0][j]
#pragma unroll 8
        for (int kb = 0; kb < NKB; ++kb)
            s += partial[((size_t)kb * BATCH + 0) * E + j];
        s_y0[t] = tanhf(s);
    }

    // 2) rc==0 blocks write full yout (8 batches x 128 cols, 4 per thread)
    if (rc == 0) {
        for (int i = t; i < BATCH * STRIPE; i += 256) {
            const int b = i >> 7;         // 0..7
            const int j = col0 + (i & (STRIPE - 1));
            float s = input[(size_t)b * E + j];
#pragma unroll 8
            for (int kb = 0; kb < NKB; ++kb)
                s += partial[((size_t)kb * BATCH + b) * E + j];
            yout[(size_t)b * E + j] = tanhf(s);
        }
    }
    __syncthreads();

    // 3) hebb tile update
    const float eta  = eta_p[0];
    const float keep = 1.0f - eta;

    const int cq = (t & 31) * 4;          // col offset within stripe (x4)
    const int rbase = rc * RCHUNK + (t >> 5);  // 8 row-phases of 8

    const float4 yo = *reinterpret_cast<const float4*>(&s_y0[cq]);

#pragma unroll
    for (int r = 0; r < 8; ++r) {
        const int row = rbase + r * 8;
        const size_t base = (size_t)row * E + col0 + cq;
        const float y0 = yin[row] * eta;  // eta * yin[0][row]

        const float4 h = *reinterpret_cast<const float4*>(hebb + base);

        f32x4 o;
        o.x = fmaf(y0, yo.x, keep * h.x);
        o.y = fmaf(y0, yo.y, keep * h.y);
        o.z = fmaf(y0, yo.z, keep * h.z);
        o.w = fmaf(y0, yo.w, keep * h.w);

        __builtin_nontemporal_store(o, reinterpret_cast<f32x4*>(hebb_out + base));
    }
}

// ---------------------------------------------------------------------------
extern "C" void kernel_launch(void* const* d_in, const int* in_sizes, int n_in,
                              void* d_out, int out_size, void* d_ws, size_t ws_size,
                              hipStream_t stream) {
    const float* input = (const float*)d_in[0];   // [8, 4096]
    const float* yin   = (const float*)d_in[1];   // [8, 4096]
    const float* hebb  = (const float*)d_in[2];   // [4096, 4096]
    const float* w     = (const float*)d_in[3];   // [4096, 4096]
    const float* alpha = (const float*)d_in[4];   // [4096, 4096]
    const float* eta   = (const float*)d_in[5];   // [1]

    float* out      = (float*)d_out;
    float* yout     = out;                               // 8*4096 floats
    float* hebb_out = out + (size_t)BATCH * E;           // 4096*4096 floats
    float* partial  = (float*)d_ws;                      // 4 MiB

    dim3 gridA(NCOLB, NKB);   // 16 x 32 = 512 blocks
    partial_gemm_kernel<<<gridA, 256, 0, stream>>>(yin, hebb, w, alpha, partial);

    dim3 gridBC(E / STRIPE, E / RCHUNK);   // 32 x 64 = 2048 blocks
    fused_bc_kernel<<<gridBC, 256, 0, stream>>>(input, partial, yin, hebb, eta,
                                                yout, hebb_out);
}

// Round 9
// 59.270 us; speedup vs baseline: 1.0064x; 1.0064x over previous
//
#include <hip/hip_runtime.h>
#include <math.h>

// Problem constants
#define E      4096
#define BATCH  8
#define COLB   256            // columns per block (64 lanes x float4)
#define KB     128            // k-rows per block (4 waves x 32)
#define NCOLB  (E / COLB)     // 16
#define NKB    (E / KB)       // 32
#define WNT_KBLOCKS 8         // w rows [0, 8*128) loaded non-temporally (16 MiB)

typedef float f32x4 __attribute__((ext_vector_type(4)));

// ---------------------------------------------------------------------------
// Kernel A: split-K partial GEMM for  yin @ (w + alpha*hebb)
//   partial[kBlock][b][col] = sum_{k in kBlock} yin[b][k] * (w[k][col] + alpha[k][col]*hebb[k][col])
// Deterministic: fixed partitioning, fixed reduction order, no atomics.
//
// L3 capacity management (R1/R4/R7 evidence): total allocating set =
// reads 196 MiB + hebb_out write-allocate 64 MiB = 260 MiB, 4 MiB over the
// 256 MiB MALL -> cyclic thrash (50% miss). Sacrifice a fixed 16 MiB slice
// of w (kBlock < 8) via non-temporal loads (always-miss, never-allocate);
// remaining allocating set = 244 MiB < 256 -> resident across graph replays.
// ---------------------------------------------------------------------------
__global__ __launch_bounds__(256) void partial_gemm_kernel(
    const float* __restrict__ yin,
    const float* __restrict__ hebb,
    const float* __restrict__ w,
    const float* __restrict__ alpha,
    float* __restrict__ partial)          // [NKB][BATCH][E]
{
    __shared__ __align__(16) float s_yin[BATCH * KB];        // 4 KiB
    __shared__ __align__(16) float s_red[4 * BATCH * COLB];  // 32 KiB

    const int t    = threadIdx.x;
    const int lane = t & 63;
    const int wave = t >> 6;              // 0..3
    const int colBlock = blockIdx.x;      // 0..15
    const int kBlock   = blockIdx.y;      // 0..31

    // Stage yin[b][kBlock*KB .. +KB) into LDS: 8 x 128 floats, float4 per thread
    {
        const int b   = t >> 5;           // 0..7
        const int off = (t & 31) * 4;     // 0..124
        const float4 v = *reinterpret_cast<const float4*>(
            yin + (size_t)b * E + (size_t)kBlock * KB + off);
        *reinterpret_cast<float4*>(&s_yin[b * KB + off]) = v;
    }
    __syncthreads();

    const int col0 = colBlock * COLB + lane * 4;

    float4 acc[BATCH];
#pragma unroll
    for (int b = 0; b < BATCH; ++b) acc[b] = make_float4(0.f, 0.f, 0.f, 0.f);

    const int kLocal0 = wave * (KB / 4);  // 32 k's per wave

    if (kBlock < WNT_KBLOCKS) {
        // nt-w variant: w loads bypass/never-allocate L3.
#pragma unroll 2
        for (int kk = 0; kk < KB / 4; ++kk) {
            const int kL = kLocal0 + kk;
            const size_t row = (size_t)(kBlock * KB + kL) * E + col0;

            const f32x4  wn = __builtin_nontemporal_load(
                                  reinterpret_cast<const f32x4*>(w + row));
            const float4 a4 = *reinterpret_cast<const float4*>(alpha + row);
            const float4 h4 = *reinterpret_cast<const float4*>(hebb + row);

            float4 m;
            m.x = wn.x + a4.x * h4.x;
            m.y = wn.y + a4.y * h4.y;
            m.z = wn.z + a4.z * h4.z;
            m.w = wn.w + a4.w * h4.w;

#pragma unroll
            for (int b = 0; b < BATCH; ++b) {
                const float yv = s_yin[b * KB + kL];
                acc[b].x = fmaf(yv, m.x, acc[b].x);
                acc[b].y = fmaf(yv, m.y, acc[b].y);
                acc[b].z = fmaf(yv, m.z, acc[b].z);
                acc[b].w = fmaf(yv, m.w, acc[b].w);
            }
        }
    } else {
        // normal variant (identical math)
#pragma unroll 2
        for (int kk = 0; kk < KB / 4; ++kk) {
            const int kL = kLocal0 + kk;
            const size_t row = (size_t)(kBlock * KB + kL) * E + col0;

            const float4 w4 = *reinterpret_cast<const float4*>(w + row);
            const float4 a4 = *reinterpret_cast<const float4*>(alpha + row);
            const float4 h4 = *reinterpret_cast<const float4*>(hebb + row);

            float4 m;
            m.x = w4.x + a4.x * h4.x;
            m.y = w4.y + a4.y * h4.y;
            m.z = w4.z + a4.z * h4.z;
            m.w = w4.w + a4.w * h4.w;

#pragma unroll
            for (int b = 0; b < BATCH; ++b) {
                const float yv = s_yin[b * KB + kL];
                acc[b].x = fmaf(yv, m.x, acc[b].x);
                acc[b].y = fmaf(yv, m.y, acc[b].y);
                acc[b].z = fmaf(yv, m.z, acc[b].z);
                acc[b].w = fmaf(yv, m.w, acc[b].w);
            }
        }
    }

    // Store per-wave accumulators: layout s_red[wave][b][COLB]
#pragma unroll
    for (int b = 0; b < BATCH; ++b) {
        *reinterpret_cast<float4*>(&s_red[(wave * BATCH + b) * COLB + lane * 4]) = acc[b];
    }
    __syncthreads();

    // Reduce 4 waves -> partial.  col = t (coalesced LDS + global).
#pragma unroll
    for (int b = 0; b < BATCH; ++b) {
        const int col = t;
        const float s = s_red[(0 * BATCH + b) * COLB + col]
                      + s_red[(1 * BATCH + b) * COLB + col]
                      + s_red[(2 * BATCH + b) * COLB + col]
                      + s_red[(3 * BATCH + b) * COLB + col];
        partial[((size_t)kBlock * BATCH + b) * E + colBlock * COLB + col] = s;
    }
}

// ---------------------------------------------------------------------------
// Kernel B: yout[b][j] = tanh(input[b][j] + sum_kb partial[kb][b][j])
// ---------------------------------------------------------------------------
__global__ __launch_bounds__(256) void finalize_yout_kernel(
    const float* __restrict__ input,
    const float* __restrict__ partial,
    float* __restrict__ yout)
{
    const int idx = blockIdx.x * 256 + threadIdx.x;   // 0..32767
    const int b = idx >> 12;
    const int j = idx & (E - 1);

    float s = input[idx];
#pragma unroll
    for (int kb = 0; kb < NKB; ++kb)
        s += partial[((size_t)kb * BATCH + b) * E + j];

    yout[idx] = tanhf(s);
}

// ---------------------------------------------------------------------------
// Kernel C: hebb_new = (1-eta)*hebb + eta * outer(yin[0], yout[0])
// hebb read: normal (should now be L3-resident). hebb_out store: nt (kept
// from R7 — neutral-to-slightly-positive).
// ---------------------------------------------------------------------------
__global__ __launch_bounds__(256) void hebb_update_kernel(
    const float* __restrict__ hebb,
    const float* __restrict__ yin,
    const float* __restrict__ yout,       // d_out row 0 (already written)
    const float* __restrict__ eta_p,
    float* __restrict__ hebb_out)
{
    const float eta  = eta_p[0];
    const float keep = 1.0f - eta;

    const size_t N4 = (size_t)E * E / 4;  // 4,194,304 float4's
    const size_t stride = (size_t)gridDim.x * blockDim.x;

    for (size_t i4 = (size_t)blockIdx.x * blockDim.x + threadIdx.x; i4 < N4; i4 += stride) {
        const size_t base = i4 * 4;
        const int row = (int)(base >> 12);          // i index
        const int jcol = (int)(base & (E - 1));     // j index (multiple of 4)

        const float y0 = yin[row] * eta;            // eta * yin[0][row]
        const float4 h  = *reinterpret_cast<const float4*>(hebb + base);
        const float4 yo = *reinterpret_cast<const float4*>(yout + jcol);

        f32x4 r;
        r.x = fmaf(y0, yo.x, keep * h.x);
        r.y = fmaf(y0, yo.y, keep * h.y);
        r.z = fmaf(y0, yo.z, keep * h.z);
        r.w = fmaf(y0, yo.w, keep * h.w);

        __builtin_nontemporal_store(r, reinterpret_cast<f32x4*>(hebb_out + base));
    }
}

// ---------------------------------------------------------------------------
extern "C" void kernel_launch(void* const* d_in, const int* in_sizes, int n_in,
                              void* d_out, int out_size, void* d_ws, size_t ws_size,
                              hipStream_t stream) {
    const float* input = (const float*)d_in[0];   // [8, 4096]
    const float* yin   = (const float*)d_in[1];   // [8, 4096]
    const float* hebb  = (const float*)d_in[2];   // [4096, 4096]
    const float* w     = (const float*)d_in[3];   // [4096, 4096]
    const float* alpha = (const float*)d_in[4];   // [4096, 4096]
    const float* eta   = (const float*)d_in[5];   // [1]

    float* out      = (float*)d_out;
    float* yout     = out;                               // 8*4096 floats
    float* hebb_out = out + (size_t)BATCH * E;           // 4096*4096 floats
    float* partial  = (float*)d_ws;                      // 4 MiB

    dim3 gridA(NCOLB, NKB);   // 16 x 32 = 512 blocks
    partial_gemm_kernel<<<gridA, 256, 0, stream>>>(yin, hebb, w, alpha, partial);

    finalize_yout_kernel<<<(BATCH * E) / 256, 256, 0, stream>>>(input, partial, yout);

    hebb_update_kernel<<<2048, 256, 0, stream>>>(hebb, yin, yout, eta, hebb_out);
}